// Round 6
// baseline (174.117 us; speedup 1.0000x reference)
//
#include <hip/hip_runtime.h>

typedef __attribute__((ext_vector_type(8))) short short8;
typedef __attribute__((ext_vector_type(4))) float f32x4;
typedef __attribute__((ext_vector_type(16))) float f32x16;
typedef __attribute__((ext_vector_type(4))) unsigned int u32x4;

#define NTOK 4096
#define DIM  256
#define TILE_ELEMS 32768   // ushort elems per 64KB tile image (Ks 16384 | Kt 16384)

__device__ __forceinline__ unsigned pack2bf(float a, float b) {
  unsigned ua = __builtin_bit_cast(unsigned, a) + 0x8000u;
  unsigned ub = __builtin_bit_cast(unsigned, b) + 0x8000u;
  return __builtin_amdgcn_perm(ub, ua, 0x07060302u); // low=bf16(a), high=bf16(b)
}

// ---- prologue v2: single X read, LDS-staged transpose (verified R3) ------
__global__ __launch_bounds__(256, 4)
void prep_kernel(const float* __restrict__ X, unsigned short* __restrict__ Img) {
  __shared__ __align__(16) unsigned short rowbf[8 * 256];  // 4 KB bf16 stage
  const int b    = blockIdx.x & 3;
  const int sub  = blockIdx.x >> 2;   // 0..511
  const int t    = sub >> 3;
  const int part = sub & 7;
  const int tid  = threadIdx.x;
  const float* src = X + ((size_t)b * NTOK + t * 64 + part * 8) * DIM;
  unsigned short* dst = Img + ((size_t)(b * 64 + t)) * TILE_ELEMS;
  {
    const int r = tid >> 5;   // row within the 8-row slab
    const int c = tid & 31;   // 16B chunk within the row
    const float* s = src + r * DIM + c * 8;
    f32x4 f0 = *(const f32x4*)s;
    f32x4 f1 = *(const f32x4*)(s + 4);
    union { unsigned u[4]; u32x4 v; } p;
    p.u[0] = pack2bf(f0[0], f0[1]);
    p.u[1] = pack2bf(f0[2], f0[3]);
    p.u[2] = pack2bf(f1[0], f1[1]);
    p.u[3] = pack2bf(f1[2], f1[3]);
    const int gr = part * 8 + r;
    *(u32x4*)(dst + gr * 256 + ((c ^ (gr & 7)) << 3)) = p.v;
    *(u32x4*)(&rowbf[r * 256 + c * 8]) = p.v;
  }
  __syncthreads();
  {
    const int d = tid;        // one column per thread
    union { unsigned short s[8]; u32x4 v; } p;
    #pragma unroll
    for (int i = 0; i < 8; ++i) p.s[i] = rowbf[i * 256 + d];
    *(u32x4*)(dst + 16384 + part * 2048 + d * 8) = p.v;
  }
}

// ---- flash-attention v6: 32x32 MFMA, 128-key tiles, 1 barrier/tile -------
// 8 waves, 512 thr, grid 256. QK: wave=(qh,kg) -> 32q x 32k sub-tile, B from
// LDS-staged Ks image (2 img tiles dbuf, 128KB). PV: wave=(qh,dg) -> 32q x
// 64d, A from XOR-swizzled P LDS (dbuf 32KB), B (V) register-resident from
// L2-hot Kt image, loaded one iter ahead (single static set). Fragment maps
// are the 2xK generalization of the verified 16x16 maps:
//   A/B: row|col = lane&31, k = kstep*16 + (lane>>5)*8 + e
//   D  : col = lane&31, row = (reg&3) + 8*(reg>>2) + 4*(lane>>5)
__global__ __launch_bounds__(512, 2)
void fa_kernel(const unsigned short* __restrict__ Img, float* __restrict__ Out) {
  __shared__ __align__(16) unsigned short ksb[2][32768]; // 128 KB: Ks dbuf (128-key images)
  __shared__ __align__(16) unsigned short pb[2][8192];   //  32 KB: P dbuf, 64r x 128k swz
  // epilogue lbuf (64x4 f32) overlays pb[0] (free after last PV(30) read)

  const int tid  = threadIdx.x;
  const int b    = blockIdx.x & 3;
  const int qblk = blockIdx.x >> 2;
  const int wave = tid >> 6;
  const int lane = tid & 63;
  const int l5   = lane & 31;
  const int h    = lane >> 5;
  const int swz  = l5 & 7;
  const int qh   = wave & 1;   // q strip (32 rows)
  const int kg   = wave >> 1;  // QK key-group / PV d-group

  const unsigned short* imgb  = Img + (size_t)b * 64 * TILE_ELEMS;
  const char*           imgbc = (const char*)imgb;

  // Q A-frags: row = qblk*64 + qh*32 + l5, k = ksl*16 + h*8 + e
  short8 aQ[16];
  {
    const unsigned short* qrow =
        imgb + (size_t)qblk * TILE_ELEMS + (qh * 32 + l5) * 256;
    #pragma unroll
    for (int k = 0; k < 16; ++k)
      aQ[k] = *(const short8*)(qrow + (((k * 2 + h) ^ swz) << 3));
  }

  f32x16 o0 = (f32x16)(0.0f), o1 = (f32x16)(0.0f);
  float lsum[16];
  #pragma unroll
  for (int r = 0; r < 16; ++r) lsum[r] = 0.f;

  const float c2 = 0.0901684400f;  // log2(e)/sqrt(256)

  // P-store constants: even lanes store regs j (rows qr(j)), odd regs j+8 (+16)
  const int psBase = (qh * 32 + ((l5 & 1) << 4) + 4 * h) * 128 + (l5 & 6);
  const int cXb    = (kg * 4 + (l5 >> 3)) ^ (h << 2);

  // V-frag base: d = kg*64 + dt*32 + l5, token-block kb = ks*2+h
  const char* vbase = imgbc + 32768 + h * 4096 + (size_t)(kg * 64 + l5) * 16;

  // Ks DMA: wave stages 8KB of the 2-tile pair (pair-half dp, quarter dq)
  const int dp = wave >> 2, dq = wave & 3;
  const char* gKs = imgbc + (size_t)dp * 65536 + dq * 8192 + (size_t)lane * 16;
  {
    unsigned short* l = &ksb[0][dp * 16384 + dq * 4096];
    #pragma unroll
    for (int i = 0; i < 8; ++i)
      __builtin_amdgcn_global_load_lds(
          (const __attribute__((address_space(1))) unsigned*)(gKs + i * 1024),
          (__attribute__((address_space(3))) unsigned*)(l + i * 512),
          16, 0, 0);
  }

  short8 vF[2][8];  // V(t) frags, consumed by PV at iter t+1

  #pragma unroll 1
  for (int t = 0; t < 32; ++t) {
    __syncthreads();  // Ks(t) + P(t-1) resident; prior reads of pb[t&1] done
    const int buf = t & 1;

    // issue Ks(t+1) DMA into the other buffer (no hazard: dbuf)
    if (t < 31) {
      const char* g = gKs + (size_t)(2 * (t + 1)) * 65536;
      unsigned short* l = &ksb[buf ^ 1][dp * 16384 + dq * 4096];
      #pragma unroll
      for (int i = 0; i < 8; ++i)
        __builtin_amdgcn_global_load_lds(
            (const __attribute__((address_space(1))) unsigned*)(g + i * 1024),
            (__attribute__((address_space(3))) unsigned*)(l + i * 512),
            16, 0, 0);
    }

    // --- QK(t): 32q x 32k, two accumulator chains ---
    f32x16 sfA = (f32x16)(0.0f), sfB = (f32x16)(0.0f);
    {
      const unsigned short* krow =
          &ksb[buf][(kg >> 1) * 16384 + ((kg & 1) * 32 + l5) * 256];
      #pragma unroll
      for (int k = 0; k < 16; k += 2) {
        short8 b0 = *(const short8*)(krow + (((k * 2 + h) ^ swz) << 3));
        short8 b1 = *(const short8*)(krow + (((k * 2 + 2 + h) ^ swz) << 3));
        sfA = __builtin_amdgcn_mfma_f32_32x32x16_bf16(aQ[k], b0, sfA, 0, 0, 0);
        sfB = __builtin_amdgcn_mfma_f32_32x32x16_bf16(aQ[k + 1], b1, sfB, 0, 0, 0);
      }
    }
    f32x16 sf = sfA + sfB;

    // --- softmax numerators (regs) ---
    float p[16];
    #pragma unroll
    for (int r = 0; r < 16; ++r) {
      p[r] = __builtin_amdgcn_exp2f(sf[r] * c2);
      lsum[r] += p[r];
    }
    // pack: each lane emits 8 dwords (even lanes: regs 0..7, odd: 8..15)
    unsigned pd[8];
    #pragma unroll
    for (int j = 0; j < 8; ++j) {
      unsigned pj  = __builtin_bit_cast(unsigned, p[j]);
      unsigned pj8 = __builtin_bit_cast(unsigned, p[j + 8]);
      unsigned dj  = (unsigned)__builtin_amdgcn_mov_dpp((int)pj, 0xB1, 0xF, 0xF, true);
      unsigned dj8 = (unsigned)__builtin_amdgcn_mov_dpp((int)pj8, 0xB1, 0xF, 0xF, true);
      float lo = (l5 & 1) ? __builtin_bit_cast(float, dj8) : p[j];
      float hi = (l5 & 1) ? p[j + 8] : __builtin_bit_cast(float, dj);
      pd[j] = pack2bf(lo, hi);
    }

    // --- PV(t-1): 32q x 64d, A from pb[buf^1], B from vF regs ---
    if (t > 0) {
      const unsigned short* prow = pb[buf ^ 1] + (qh * 32 + l5) * 128;
      #pragma unroll
      for (int ks = 0; ks < 8; ++ks) {
        short8 pA = *(const short8*)(prow + (((ks * 2 + h) ^ swz) << 3));
        o0 = __builtin_amdgcn_mfma_f32_32x32x16_bf16(pA, vF[0][ks], o0, 0, 0, 0);
        o1 = __builtin_amdgcn_mfma_f32_32x32x16_bf16(pA, vF[1][ks], o1, 0, 0, 0);
      }
    }

    // --- refill vF = V(t) from Kt image (L2-hot; full iter to land) ---
    {
      const char* vb = vbase + (size_t)(2 * t) * 65536;
      #pragma unroll
      for (int ks = 0; ks < 8; ++ks) {
        const int off = ks * 8192 + (ks >= 4 ? 32768 : 0);
        vF[0][ks] = *(const short8*)(vb + off);
        vF[1][ks] = *(const short8*)(vb + off + 512);
      }
    }

    // --- P-store(t) into pb[buf] (disjoint from PV's pb[buf^1]) ---
    {
      unsigned short* pw = pb[buf];
      #pragma unroll
      for (int j = 0; j < 8; ++j) {
        const int off = psBase + ((j & 3) + 8 * (j >> 2)) * 128 +
                        ((cXb ^ (j & 3)) << 3);
        *(unsigned*)(&pw[off]) = pd[j];
      }
    }
  }

  __syncthreads();  // P(31) resident, vF = V(31)
  // --- final PV(31) ---
  {
    const unsigned short* prow = pb[1] + (qh * 32 + l5) * 128;
    #pragma unroll
    for (int ks = 0; ks < 8; ++ks) {
      short8 pA = *(const short8*)(prow + (((ks * 2 + h) ^ swz) << 3));
      o0 = __builtin_amdgcn_mfma_f32_32x32x16_bf16(pA, vF[0][ks], o0, 0, 0, 0);
      o1 = __builtin_amdgcn_mfma_f32_32x32x16_bf16(pA, vF[1][ks], o1, 0, 0, 0);
    }
  }

  // --- merge lsum: reduce over the 32 keys (l5) then across kg via lbuf ---
  #pragma unroll
  for (int off = 1; off < 32; off <<= 1)
    #pragma unroll
    for (int r = 0; r < 16; ++r)
      lsum[r] += __shfl_xor(lsum[r], off, 64);

  float (*lbufF)[4] = (float(*)[4])(&pb[0][0]);  // overlay, disjoint from pb[1]
  if (l5 == 0) {
    #pragma unroll
    for (int r = 0; r < 16; ++r)
      lbufF[qh * 32 + (r & 3) + 8 * (r >> 2) + 4 * h][kg] = lsum[r];
  }
  __syncthreads();

  float* outp = Out + (size_t)(b * NTOK + qblk * 64) * DIM;
  #pragma unroll
  for (int r = 0; r < 16; ++r) {
    const int row = qh * 32 + (r & 3) + 8 * (r >> 2) + 4 * h;
    f32x4 lv = *(const f32x4*)lbufF[row];
    const float rl = 1.0f / (lv[0] + lv[1] + lv[2] + lv[3]);
    outp[(size_t)row * DIM + kg * 64 + l5]      = o0[r] * rl;
    outp[(size_t)row * DIM + kg * 64 + 32 + l5] = o1[r] * rl;
  }
}

extern "C" void kernel_launch(void* const* d_in, const int* in_sizes, int n_in,
                              void* d_out, int out_size, void* d_ws, size_t ws_size,
                              hipStream_t stream) {
  const float* X = (const float*)d_in[0];       // x: fp32 [4,4096,256]
  float* Out = (float*)d_out;                   // fp32 [4,4096,256]
  unsigned short* Img = (unsigned short*)d_ws;  // 16 MB bf16 tile images
  (void)in_sizes; (void)n_in; (void)out_size; (void)ws_size;
  hipLaunchKernelGGL(prep_kernel, dim3(2048), dim3(256), 0, stream, X, Img);
  hipLaunchKernelGGL(fa_kernel, dim3(256), dim3(512), 0, stream, Img, Out);
}